// Round 1
// baseline (645.158 us; speedup 1.0000x reference)
//
#include <hip/hip_runtime.h>
#include <math.h>

#define NPTS_DEF 524288
#define LVLS 8
#define TSZ (1u << 19)

struct ResArr { float r[8]; };

__device__ __forceinline__ float relu_f(float x) { return fmaxf(x, 0.0f); }

// acc[j] = b[j] + sum_{k<IN} actc[k][tid] * W[k*64+j]   (j = 0..63)
// W/b addresses are wave-uniform -> scalar loads; actc[k][tid] -> ds_read.
__device__ __forceinline__ void dense64(const float* __restrict__ W,
                                        const float* __restrict__ b,
                                        const float (*actc)[64], int IN, int tid,
                                        float acc[64])
{
#pragma unroll
    for (int j = 0; j < 64; ++j) acc[j] = b[j];
    for (int k = 0; k < IN; ++k) {
        float a = actc[k][tid];
        const float* wr = W + k * 64;
#pragma unroll
        for (int j = 0; j < 64; ++j) acc[j] = fmaf(a, wr[j], acc[j]);
    }
}

__global__ void __launch_bounds__(64, 4) ngp_fused(
    const float* __restrict__ pts, const float* __restrict__ views,
    const float* __restrict__ tables,
    const float* __restrict__ W1, const float* __restrict__ b1,
    const float* __restrict__ W2, const float* __restrict__ b2,
    const float* __restrict__ W3, const float* __restrict__ b3,
    const float* __restrict__ W4, const float* __restrict__ b4,
    const float* __restrict__ W5, const float* __restrict__ b5,
    const float* __restrict__ W6, const float* __restrict__ b6,
    const float* __restrict__ W7, const float* __restrict__ b7,
    ResArr res, float* __restrict__ out_col, float* __restrict__ out_den,
    int npts)
{
    // activations: [neuron k][tid] — each thread only touches its own column,
    // so no __syncthreads needed; lane->consecutive addresses => 2 lanes/bank (free).
    __shared__ float act[64][64];
    const int tid = threadIdx.x;
    const int n = blockIdx.x * 64 + tid;
    if (n >= npts) return;

    const float px = pts[3 * n + 0];
    const float py = pts[3 * n + 1];
    const float pz = pts[3 * n + 2];

    // ---- hash grid encode: 8 levels, 8 corners, trilinear ----
#pragma unroll
    for (int l = 0; l < LVLS; ++l) {
        float r = res.r[l];
        float fx = px * r, fy = py * r, fz = pz * r;
        float f0x = floorf(fx), f0y = floorf(fy), f0z = floorf(fz);
        unsigned ix = (unsigned)f0x, iy = (unsigned)f0y, iz = (unsigned)f0z;
        float tx = fx - f0x, ty = fy - f0y, tz = fz - f0z;
        const float4* tbl = (const float4*)tables + (size_t)l * TSZ;
        float4 a = make_float4(0.f, 0.f, 0.f, 0.f);
#pragma unroll
        for (int c = 0; c < 8; ++c) {
            unsigned ux = ix + ((c >> 2) & 1);
            unsigned uy = iy + ((c >> 1) & 1);
            unsigned uz = iz + (c & 1);
            unsigned h = (ux * 1u) ^ (uy * 2654435761u) ^ (uz * 805459861u);
            h &= (TSZ - 1u);
            float4 f = tbl[h];
            float w = ((c & 4) ? tx : 1.0f - tx) *
                      ((c & 2) ? ty : 1.0f - ty) *
                      ((c & 1) ? tz : 1.0f - tz);
            a.x = fmaf(w, f.x, a.x);
            a.y = fmaf(w, f.y, a.y);
            a.z = fmaf(w, f.z, a.z);
            a.w = fmaf(w, f.w, a.w);
        }
        act[l * 4 + 0][tid] = a.x;
        act[l * 4 + 1][tid] = a.y;
        act[l * 4 + 2][tid] = a.z;
        act[l * 4 + 3][tid] = a.w;
    }

    float acc[64];

    // ---- density net ----
    dense64(W1, b1, act, 32, tid, acc);
#pragma unroll
    for (int j = 0; j < 64; ++j) act[j][tid] = relu_f(acc[j]);

    dense64(W2, b2, act, 64, tid, acc);
#pragma unroll
    for (int j = 0; j < 64; ++j) act[j][tid] = relu_f(acc[j]);

    float acc3[16];
#pragma unroll
    for (int j = 0; j < 16; ++j) acc3[j] = b3[j];
    for (int k = 0; k < 64; ++k) {
        float aa = act[k][tid];
        const float* wr = W3 + k * 16;
#pragma unroll
        for (int j = 0; j < 16; ++j) acc3[j] = fmaf(aa, wr[j], acc3[j]);
    }
    float density = relu_f(acc3[0]);

    // ---- SH4 view encoding ----
    float vx = views[3 * n + 0], vy = views[3 * n + 1], vz = views[3 * n + 2];
    float inv = rsqrtf(vx * vx + vy * vy + vz * vz);
    vx *= inv; vy *= inv; vz *= inv;
    float xx = vx * vx, yy = vy * vy, zz = vz * vz;
    float sh[16];
    sh[0]  = 0.28209479177387814f;
    sh[1]  = -0.48860251190291987f * vy;
    sh[2]  = 0.48860251190291987f * vz;
    sh[3]  = -0.48860251190291987f * vx;
    sh[4]  = 1.0925484305920792f * vx * vy;
    sh[5]  = -1.0925484305920792f * vy * vz;
    sh[6]  = 0.94617469575755997f * zz - 0.31539156525252005f;
    sh[7]  = -1.0925484305920792f * vx * vz;
    sh[8]  = 0.54627421529603959f * (xx - yy);
    sh[9]  = -0.59004358992664352f * vy * (3.0f * xx - yy);
    sh[10] = 2.8906114426405538f * vx * vy * vz;
    sh[11] = -0.45704579946446572f * vy * (4.0f * zz - xx - yy);
    sh[12] = 0.37317633259011546f * vz * (2.0f * zz - 3.0f * xx - 3.0f * yy);
    sh[13] = -0.45704579946446572f * vx * (4.0f * zz - xx - yy);
    sh[14] = 1.4453057213202769f * vz * (xx - yy);
    sh[15] = -0.59004358992664352f * vx * (xx - 3.0f * yy);

    // ---- color net input: [x3[1:16], sh[0:16]] = 31 dims ----
#pragma unroll
    for (int k = 0; k < 15; ++k) act[k][tid] = acc3[1 + k];
#pragma unroll
    for (int k = 0; k < 16; ++k) act[15 + k][tid] = sh[k];

    dense64(W4, b4, act, 31, tid, acc);
#pragma unroll
    for (int j = 0; j < 64; ++j) act[j][tid] = relu_f(acc[j]);

    dense64(W5, b5, act, 64, tid, acc);
#pragma unroll
    for (int j = 0; j < 64; ++j) act[j][tid] = relu_f(acc[j]);

    dense64(W6, b6, act, 64, tid, acc);
#pragma unroll
    for (int j = 0; j < 64; ++j) act[j][tid] = relu_f(acc[j]);

    float c3[3];
#pragma unroll
    for (int j = 0; j < 3; ++j) c3[j] = b7[j];
    for (int k = 0; k < 64; ++k) {
        float aa = act[k][tid];
        const float* wr = W7 + k * 3;
#pragma unroll
        for (int j = 0; j < 3; ++j) c3[j] = fmaf(aa, wr[j], c3[j]);
    }

#pragma unroll
    for (int j = 0; j < 3; ++j)
        out_col[3 * (size_t)n + j] = 1.0f / (1.0f + expf(-c3[j]));
    out_den[n] = density;
}

extern "C" void kernel_launch(void* const* d_in, const int* in_sizes, int n_in,
                              void* d_out, int out_size, void* d_ws, size_t ws_size,
                              hipStream_t stream) {
    const float* pts    = (const float*)d_in[0];
    const float* views  = (const float*)d_in[1];
    const float* tables = (const float*)d_in[2];
    const float* W1 = (const float*)d_in[3];  const float* b1 = (const float*)d_in[4];
    const float* W2 = (const float*)d_in[5];  const float* b2 = (const float*)d_in[6];
    const float* W3 = (const float*)d_in[7];  const float* b3 = (const float*)d_in[8];
    const float* W4 = (const float*)d_in[9];  const float* b4 = (const float*)d_in[10];
    const float* W5 = (const float*)d_in[11]; const float* b5 = (const float*)d_in[12];
    const float* W6 = (const float*)d_in[13]; const float* b6 = (const float*)d_in[14];
    const float* W7 = (const float*)d_in[15]; const float* b7 = (const float*)d_in[16];

    const int N = in_sizes[0] / 3;
    float* out = (float*)d_out;
    float* out_col = out;                       // [N,3]
    float* out_den = out + (size_t)3 * N;       // [N]

    ResArr res;
    for (int l = 0; l < 8; ++l)
        res.r[l] = (float)(16.0 * pow(64.0, (double)l / 7.0));

    const int grid = (N + 63) / 64;
    ngp_fused<<<grid, 64, 0, stream>>>(pts, views, tables,
                                       W1, b1, W2, b2, W3, b3, W4, b4,
                                       W5, b5, W6, b6, W7, b7,
                                       res, out_col, out_den, N);
}